// Round 14
// baseline (809.806 us; speedup 1.0000x reference)
//
#include <hip/hip_runtime.h>

typedef __attribute__((ext_vector_type(8))) short bf16x8;
typedef __attribute__((ext_vector_type(4))) short s16x4;
typedef __attribute__((ext_vector_type(4))) float f32x4;

#define MFMA16(a,b,c) __builtin_amdgcn_mfma_f32_16x16x32_bf16((a),(b),(c),0,0,0)

__device__ __forceinline__ unsigned short f2bf(float f) {
  unsigned int u = __float_as_uint(f);
  return (unsigned short)((u + 0x7fffu + ((u >> 16) & 1u)) >> 16);  // RNE
}
__device__ __forceinline__ float bf2f(unsigned short u) {
  return __uint_as_float(((unsigned int)u) << 16);
}

__device__ __forceinline__ void gload16(const void* g, void* l) {
  __builtin_amdgcn_global_load_lds((const __attribute__((address_space(1))) void*)g,
                                   (__attribute__((address_space(3))) void*)l, 16, 0, 0);
}

// ---- f32 -> bf16 bulk convert ----
__global__ __launch_bounds__(256) void cvt_bf16(const float* __restrict__ in,
                                                unsigned short* __restrict__ out, int n8) {
  for (int i = blockIdx.x * 256 + threadIdx.x; i < n8; i += gridDim.x * 256) {
    float4 a = ((const float4*)in)[2 * i];
    float4 b = ((const float4*)in)[2 * i + 1];
    s16x4 p0, p1;
    p0[0] = f2bf(a.x); p0[1] = f2bf(a.y); p0[2] = f2bf(a.z); p0[3] = f2bf(a.w);
    p1[0] = f2bf(b.x); p1[1] = f2bf(b.y); p1[2] = f2bf(b.z); p1[3] = f2bf(b.w);
    ((s16x4*)out)[2 * i] = p0;
    ((s16x4*)out)[2 * i + 1] = p1;
  }
}

// ---- W[K][N] f32 -> Wt[N][K] bf16 ----
__global__ __launch_bounds__(256) void tcvt(const float* __restrict__ W,
                                            unsigned short* __restrict__ Wt, int K, int N) {
  __shared__ float t[32][33];
  const int n0 = blockIdx.x * 32, k0 = blockIdx.y * 32;
  const int c = threadIdx.x & 31, r8 = threadIdx.x >> 5;
#pragma unroll
  for (int p = 0; p < 4; ++p) {
    int r = r8 + p * 8;
    t[r][c] = W[(size_t)(k0 + r) * N + n0 + c];
  }
  __syncthreads();
#pragma unroll
  for (int p = 0; p < 4; ++p) {
    int r = r8 + p * 8;
    Wt[(size_t)(n0 + r) * K + k0 + c] = f2bf(t[c][r]);
  }
}

// ---- projection GEMM (128x128, bf16 out): C = A[M,1024] @ Bt[N,1024]^T ----
__global__ __launch_bounds__(256) void proj_gemm(
    const unsigned short* __restrict__ A, const unsigned short* __restrict__ Bt,
    unsigned short* __restrict__ C, int N, float scale)
{
  __shared__ __align__(16) unsigned short As[2][4096];
  __shared__ __align__(16) unsigned short Bs[2][4096];
  const int tid = threadIdx.x, lane = tid & 63, w = tid >> 6;
  const int wr = w >> 1, wc = w & 1;
  const int lrow = lane & 15, lg = lane >> 4;
  const size_t bm = (size_t)blockIdx.x * 128;
  const size_t bn = (size_t)blockIdx.y * 128;
  const int rl = lane >> 2, cq = lane & 3;

  auto stage = [&](int kt, int buf) {
#pragma unroll
    for (int u = 0; u < 2; ++u) {
      int row = w * 32 + u * 16 + rl;
      gload16(A  + (bm + row) * 1024 + kt * 32 + cq * 8, &As[buf][(w * 32 + u * 16) * 32]);
      gload16(Bt + (bn + row) * 1024 + kt * 32 + cq * 8, &Bs[buf][(w * 32 + u * 16) * 32]);
    }
  };

  f32x4 acc[4][4] = {};
  stage(0, 0);
  __syncthreads();

  for (int kt = 0; kt < 32; ++kt) {
    const int cur = kt & 1;
    if (kt + 1 < 32) stage(kt + 1, cur ^ 1);
    bf16x8 af[4], bfr[4];
#pragma unroll
    for (int i = 0; i < 4; ++i)
      af[i] = *(const bf16x8*)&As[cur][(wr * 64 + i * 16 + lrow) * 32 + lg * 8];
#pragma unroll
    for (int j = 0; j < 4; ++j)
      bfr[j] = *(const bf16x8*)&Bs[cur][(wc * 64 + j * 16 + lrow) * 32 + lg * 8];
    __builtin_amdgcn_s_setprio(1);
#pragma unroll
    for (int i = 0; i < 4; ++i)
#pragma unroll
      for (int j = 0; j < 4; ++j)
        acc[i][j] = MFMA16(af[i], bfr[j], acc[i][j]);
    __builtin_amdgcn_s_setprio(0);
    __syncthreads();
  }

  const int orow0 = blockIdx.x * 128 + wr * 64;
  const int ocol0 = blockIdx.y * 128 + wc * 64;
#pragma unroll
  for (int i = 0; i < 4; ++i)
#pragma unroll
    for (int j = 0; j < 4; ++j) {
      int col = ocol0 + j * 16 + lrow;
#pragma unroll
      for (int r = 0; r < 4; ++r) {
        int row = orow0 + i * 16 + lg * 4 + r;
        C[(size_t)row * N + col] = f2bf(acc[i][j][r] * scale);
      }
    }
}

// ======================================================================
// 4-phase 256x256 bf16 GEMM (BK=64), cross-phase ds_read pipelining.
// MODE 0: bf16 C [nb][2048][2048] (sgemm).
// MODE 2: fp8 packed V: C8[b][eg=e/16][tw=m/64 in batch][e%16][m%64].
// ======================================================================
#define SBAR  do { __builtin_amdgcn_s_barrier(); __builtin_amdgcn_sched_barrier(0); } while (0)

template<int NT, int NTIL, int MODE>
__global__ __launch_bounds__(512) void gemm4p(
    const unsigned short* __restrict__ Aall, const unsigned short* __restrict__ Ball,
    size_t abatch, size_t bbatch, int lda, int ldb,
    unsigned short* __restrict__ Cb, int b0, int nb)
{
  __shared__ __align__(16) unsigned short lds[65536];  // 128 KB
  const int bid = blockIdx.x;
  const int bloc = bid % nb, tl = bid / nb;
  const int mtile = tl / NTIL, ntile = tl % NTIL;
  const int gb = b0 + bloc;
  const unsigned short* Ag = Aall + (MODE == 0 ? (size_t)gb : (size_t)bloc) * abatch
                                  + (size_t)mtile * 256 * lda;
  const unsigned short* Bg = Ball + (size_t)gb * bbatch + (size_t)ntile * 256 * ldb;

  const int tid = threadIdx.x, lane = tid & 63, w = tid >> 6;
  const int wm = w >> 2, wn = w & 3;
  const int lrow = lane & 15, lg = lane >> 4;
  char* lb = (char*)lds;

  auto stageU = [&](const unsigned short* G, int ld, int kofs, int ubyte) {
#pragma unroll
    for (int i = 0; i < 2; ++i) {
      int c = tid + 512 * i;
      int row = c >> 2, q = c & 3;
      int qs = q ^ ((row >> 1) & 3);
      gload16(G + (size_t)row * ld + kofs + qs * 8, lb + ubyte + c * 16);
    }
  };
  auto rdfrag = [&](int ubyte, int row) -> bf16x8 {
    return *(const bf16x8*)(lb + ubyte + row * 64 + ((lg ^ ((row >> 1) & 3)) << 4));
  };

  f32x4 acc[8][4] = {};
  bf16x8 afA[4], afB[4], bfrA[4], bfrB[4];

  stageU(Ag, lda, 0,  (0 * 2 + 0) * 16384);
  stageU(Bg, ldb, 0,  (1 * 2 + 0) * 16384);
  stageU(Ag, lda, 32, (2 * 2 + 0) * 16384);
  stageU(Bg, ldb, 32, (3 * 2 + 0) * 16384);
  stageU(Ag, lda, 64, (0 * 2 + 1) * 16384);
  stageU(Bg, ldb, 64, (1 * 2 + 1) * 16384);
  asm volatile("s_waitcnt vmcnt(8)" ::: "memory");
  SBAR;
#pragma unroll
  for (int i = 0; i < 4; ++i) afA[i] = rdfrag(0, wm * 128 + i * 16 + lrow);
#pragma unroll
  for (int nf = 0; nf < 4; ++nf) bfrA[nf] = rdfrag(2 * 16384, wn * 64 + nf * 16 + lrow);

  for (int T = 0; T < NT; ++T) {
    const int pc = T & 1, pn = (T + 1) & 1;
    const int a1b = (2 * 2 + pc) * 16384, b1b = (3 * 2 + pc) * 16384;
    const int a0b = (0 * 2 + pc) * 16384;
    const int t1 = (T + 1 < NT) ? T + 1 : 0;
    const int t2 = (T + 2 < NT) ? T + 2 : 0;

#pragma unroll
    for (int i = 0; i < 4; ++i) afB[i] = rdfrag(a0b, wm * 128 + (i + 4) * 16 + lrow);
    stageU(Ag, lda, t1 * 64 + 32, (2 * 2 + pn) * 16384);
    asm volatile("s_waitcnt lgkmcnt(4)" ::: "memory");
    __builtin_amdgcn_sched_barrier(0);
    __builtin_amdgcn_s_setprio(1);
#pragma unroll
    for (int mf = 0; mf < 4; ++mf)
#pragma unroll
      for (int nf = 0; nf < 4; ++nf)
        acc[mf][nf] = MFMA16(afA[mf], bfrA[nf], acc[mf][nf]);
    __builtin_amdgcn_s_setprio(0);
    asm volatile("s_waitcnt vmcnt(6)" ::: "memory");
    SBAR;

#pragma unroll
    for (int i = 0; i < 4; ++i) afA[i] = rdfrag(a1b, wm * 128 + i * 16 + lrow);
#pragma unroll
    for (int nf = 0; nf < 4; ++nf) bfrB[nf] = rdfrag(b1b, wn * 64 + nf * 16 + lrow);
    stageU(Bg, ldb, t1 * 64 + 32, (3 * 2 + pn) * 16384);
    asm volatile("s_waitcnt lgkmcnt(8)" ::: "memory");
    __builtin_amdgcn_sched_barrier(0);
    __builtin_amdgcn_s_setprio(1);
#pragma unroll
    for (int mf = 0; mf < 4; ++mf)
#pragma unroll
      for (int nf = 0; nf < 4; ++nf)
        acc[mf + 4][nf] = MFMA16(afB[mf], bfrA[nf], acc[mf + 4][nf]);
    __builtin_amdgcn_s_setprio(0);
    SBAR;

#pragma unroll
    for (int i = 0; i < 4; ++i) afB[i] = rdfrag(a1b, wm * 128 + (i + 4) * 16 + lrow);
    stageU(Ag, lda, t2 * 64, (0 * 2 + pc) * 16384);
    asm volatile("s_waitcnt lgkmcnt(4)" ::: "memory");
    __builtin_amdgcn_sched_barrier(0);
    __builtin_amdgcn_s_setprio(1);
#pragma unroll
    for (int mf = 0; mf < 4; ++mf)
#pragma unroll
      for (int nf = 0; nf < 4; ++nf)
        acc[mf][nf] = MFMA16(afA[mf], bfrB[nf], acc[mf][nf]);
    __builtin_amdgcn_s_setprio(0);
    asm volatile("s_waitcnt vmcnt(6)" ::: "memory");
    SBAR;

#pragma unroll
    for (int i = 0; i < 4; ++i) afA[i] = rdfrag((0 * 2 + pn) * 16384, wm * 128 + i * 16 + lrow);
#pragma unroll
    for (int nf = 0; nf < 4; ++nf) bfrA[nf] = rdfrag((1 * 2 + pn) * 16384, wn * 64 + nf * 16 + lrow);
    stageU(Bg, ldb, t2 * 64, (1 * 2 + pc) * 16384);
    asm volatile("s_waitcnt lgkmcnt(8)" ::: "memory");
    __builtin_amdgcn_sched_barrier(0);
    __builtin_amdgcn_s_setprio(1);
#pragma unroll
    for (int mf = 0; mf < 4; ++mf)
#pragma unroll
      for (int nf = 0; nf < 4; ++nf)
        acc[mf + 4][nf] = MFMA16(afB[mf], bfrB[nf], acc[mf + 4][nf]);
    __builtin_amdgcn_s_setprio(0);
    SBAR;
  }

  if (MODE == 0) {
    unsigned short* Cp = Cb + (size_t)bloc * 2048 * 2048;
#pragma unroll
    for (int mf = 0; mf < 8; ++mf)
#pragma unroll
      for (int r = 0; r < 4; ++r) {
        int row = mtile * 256 + wm * 128 + mf * 16 + lg * 4 + r;
#pragma unroll
        for (int nf = 0; nf < 4; ++nf) {
          int col = ntile * 256 + wn * 64 + nf * 16 + lrow;
          Cp[(size_t)row * 2048 + col] = f2bf(acc[mf][nf][r]);
        }
      }
  } else {
    // packed fp8 V: [b][eg][tw][e%16][t%64]
    unsigned char* C8 = (unsigned char*)Cb;
#pragma unroll
    for (int mf = 0; mf < 8; ++mf) {
      int m0 = mtile * 256 + wm * 128 + mf * 16 + lg * 4;  // 4 consecutive t
      int bb = m0 >> 11, t = m0 & 2047;
      int tw = t >> 6, t64 = t & 63;
#pragma unroll
      for (int nf = 0; nf < 4; ++nf) {
        int e = ntile * 256 + wn * 64 + nf * 16 + lrow;    // e%16 == lrow
        int eg = e >> 4;
        int pk = 0;
        pk = __builtin_amdgcn_cvt_pk_fp8_f32(acc[mf][nf][0], acc[mf][nf][1], pk, false);
        pk = __builtin_amdgcn_cvt_pk_fp8_f32(acc[mf][nf][2], acc[mf][nf][3], pk, true);
        *(unsigned int*)(C8 + (size_t)bb * 2097152
                            + ((size_t)(eg * 32 + tw)) * 1024 + lrow * 64 + t64)
            = (unsigned int)pk;
      }
    }
  }
}

// ---- softmax: read S bf16, write P fp8 e4m3 scaled x64. 1 wave / row ----
__global__ __launch_bounds__(256) void softmax_kernel(
    const unsigned short* __restrict__ Sp, unsigned char* __restrict__ Pp) {
  const int row = blockIdx.x * 4 + (threadIdx.x >> 6);
  const int lane = threadIdx.x & 63;
  const unsigned short* rp = Sp + (size_t)row * 2048;
  bf16x8 raw[4];
#pragma unroll
  for (int c = 0; c < 4; ++c) raw[c] = *(const bf16x8*)(rp + c * 512 + lane * 8);
  float v[32];
#pragma unroll
  for (int c = 0; c < 4; ++c)
#pragma unroll
    for (int j = 0; j < 8; ++j) v[c * 8 + j] = bf2f((unsigned short)raw[c][j]);
  float mx = v[0];
#pragma unroll
  for (int j = 1; j < 32; ++j) mx = fmaxf(mx, v[j]);
  mx = fmaxf(mx, __shfl_xor(mx, 1));
  mx = fmaxf(mx, __shfl_xor(mx, 2));
  mx = fmaxf(mx, __shfl_xor(mx, 4));
  mx = fmaxf(mx, __shfl_xor(mx, 8));
  mx = fmaxf(mx, __shfl_xor(mx, 16));
  mx = fmaxf(mx, __shfl_xor(mx, 32));
  float sum = 0.f;
#pragma unroll
  for (int j = 0; j < 32; ++j) { v[j] = __expf(v[j] - mx); sum += v[j]; }
  sum += __shfl_xor(sum, 1);
  sum += __shfl_xor(sum, 2);
  sum += __shfl_xor(sum, 4);
  sum += __shfl_xor(sum, 8);
  sum += __shfl_xor(sum, 16);
  sum += __shfl_xor(sum, 32);
  const float scale = 64.0f / sum;
  unsigned char* rp8 = Pp + (size_t)row * 2048;
#pragma unroll
  for (int c = 0; c < 4; ++c) {
    int lo = 0, hi = 0;
    lo = __builtin_amdgcn_cvt_pk_fp8_f32(v[c * 8 + 0] * scale, v[c * 8 + 1] * scale, lo, false);
    lo = __builtin_amdgcn_cvt_pk_fp8_f32(v[c * 8 + 2] * scale, v[c * 8 + 3] * scale, lo, true);
    hi = __builtin_amdgcn_cvt_pk_fp8_f32(v[c * 8 + 4] * scale, v[c * 8 + 5] * scale, hi, false);
    hi = __builtin_amdgcn_cvt_pk_fp8_f32(v[c * 8 + 6] * scale, v[c * 8 + 7] * scale, hi, true);
    uint2 o; o.x = (unsigned int)lo; o.y = (unsigned int)hi;
    *(uint2*)(rp8 + c * 512 + lane * 8) = o;
  }
}

// ======================================================================
// fp8 PV GEMM, 256x128 tile, 3 blocks/CU: A (P) in LDS (3 x 16KB tri-buf,
// stage 2 ahead), B (V) direct from packed global (L2-hot, XCD-pinned).
// acc[8][2]=64 regs.
// ======================================================================
__global__ __launch_bounds__(512, 6) void pvf8_kernel(
    const unsigned char* __restrict__ Pp,   // [nb][2048][2048] fp8 (x64)
    const unsigned char* __restrict__ Vp,   // [16] packed [64][32][16][64] fp8
    const float* __restrict__ X, float* __restrict__ Out,
    int b0, int nb)
{
  __shared__ __align__(16) unsigned char lds[3][16384];
  const int bloc = blockIdx.x % nb, tl = blockIdx.x / nb;
  const int mtile = tl >> 3, ntile = tl & 7;   // 8 mtiles x 8 ntiles
  const int gb = b0 + bloc;
  const unsigned char* Ag = Pp + (size_t)bloc * 4194304 + (size_t)mtile * 256 * 2048;
  const unsigned char* Vb = Vp + (size_t)gb * 2097152;
  const int NT = 32;
  const int tid = threadIdx.x, lane = tid & 63, w = tid >> 6;
  const int wm = w >> 2, wn = w & 3;           // 2 x 4 waves over 256 x 128
  const int lrow = lane & 15, lg = lane >> 4;

  auto stageA = [&](int jt) {
    unsigned char* dst = lds[jt % 3];
#pragma unroll
    for (int i = 0; i < 2; ++i) {
      int c = tid + 512 * i; int row = c >> 2; int q = (c & 3) ^ ((row >> 1) & 3);
      gload16(Ag + (size_t)row * 2048 + jt * 64 + q * 16, dst + c * 16);
    }
  };

  f32x4 acc[8][2] = {};
  stageA(0); stageA(1);
  asm volatile("s_waitcnt vmcnt(2)" ::: "memory");   // A(0) landed

  for (int jt = 0; jt < NT; ++jt) {
    __builtin_amdgcn_s_barrier();
    // B direct (packed V, 1KB/wave-frag, L2-hot) — issued BEFORE the stage
    long2 bv[2];
#pragma unroll
    for (int nf = 0; nf < 2; ++nf) {
      int eg = ntile * 8 + wn * 2 + nf;
      bv[nf] = *(const long2*)(Vb + ((size_t)(eg * 32 + jt)) * 1024 + lrow * 64 + lg * 16);
    }
    if (jt + 2 < NT) stageA(jt + 2);   // slot (jt-1)%3: readers drained pre-barrier
    const unsigned char* Ab = lds[jt % 3];
    // first half: rows 0..63
    {
      long2 av[4];
#pragma unroll
      for (int mf = 0; mf < 4; ++mf) {
        int row = wm * 128 + mf * 16 + lrow;
        av[mf] = *(const long2*)(Ab + row * 64 + ((lg ^ ((row >> 1) & 3)) << 4));
      }
      __builtin_amdgcn_s_setprio(1);
#pragma unroll
      for (int mf = 0; mf < 4; ++mf)
#pragma unroll
        for (int nf = 0; nf < 2; ++nf) {
          acc[mf][nf] = __builtin_amdgcn_mfma_f32_16x16x32_fp8_fp8(av[mf].x, bv[nf].x, acc[mf][nf], 0, 0, 0);
          acc[mf][nf] = __builtin_amdgcn_mfma_f32_16x16x32_fp8_fp8(av[mf].y, bv[nf].y, acc[mf][nf], 0, 0, 0);
        }
      __builtin_amdgcn_s_setprio(0);
    }
    // second half: rows 64..127
    {
      long2 av[4];
#pragma unroll
      for (int mf = 0; mf < 4; ++mf) {
        int row = wm * 128 + (mf + 4) * 16 + lrow;
        av[mf] = *(const long2*)(Ab + row * 64 + ((lg ^ ((row >> 1) & 3)) << 4));
      }
      __builtin_amdgcn_s_setprio(1);
#pragma unroll
      for (int mf = 0; mf < 4; ++mf)
#pragma unroll
        for (int nf = 0; nf < 2; ++nf) {
          acc[mf + 4][nf] = __builtin_amdgcn_mfma_f32_16x16x32_fp8_fp8(av[mf].x, bv[nf].x, acc[mf + 4][nf], 0, 0, 0);
          acc[mf + 4][nf] = __builtin_amdgcn_mfma_f32_16x16x32_fp8_fp8(av[mf].y, bv[nf].y, acc[mf + 4][nf], 0, 0, 0);
        }
      __builtin_amdgcn_s_setprio(0);
    }
  }

#pragma unroll
  for (int mf = 0; mf < 8; ++mf)
#pragma unroll
    for (int r = 0; r < 4; ++r) {
      int row = mtile * 256 + wm * 128 + mf * 16 + lg * 4 + r;
      const float* xr = X   + ((size_t)gb * 2048 + row) * 1024;
      float*      orp = Out + ((size_t)gb * 2048 + row) * 1024;
#pragma unroll
      for (int nf = 0; nf < 2; ++nf) {
        int col = ntile * 128 + wn * 32 + nf * 16 + lrow;
        orp[col] = acc[mf][nf][r] * 0.015625f + xr[col];   // /64 un-scale
      }
    }
}

extern "C" void kernel_launch(void* const* d_in, const int* in_sizes, int n_in,
                              void* d_out, int out_size, void* d_ws, size_t ws_size,
                              hipStream_t stream) {
  (void)in_sizes; (void)n_in; (void)out_size;
  const float* x  = (const float*)d_in[0];
  const float* y  = (const float*)d_in[1];
  const float* Wq = (const float*)d_in[2];
  const float* Wk = (const float*)d_in[3];
  const float* Wv = (const float*)d_in[4];
  float* out = (float*)d_out;

  // bf16 copies of x,y live in d_out during projections (overwritten later)
  unsigned short* xb = (unsigned short*)d_out;
  unsigned short* yb = xb + (size_t)16 * 2048 * 1024;

  // ws: Wqt | Wkt | Wvt (bf16) | q | k (bf16) | Vp (fp8 packed) | S (bf16) | P (fp8)
  char* p = (char*)d_ws;
  unsigned short* Wqt = (unsigned short*)p;  p += (size_t)256 * 1024 * 2;
  unsigned short* Wkt = (unsigned short*)p;  p += (size_t)256 * 1024 * 2;
  unsigned short* Wvt = (unsigned short*)p;  p += (size_t)1024 * 1024 * 2;
  unsigned short* qws = (unsigned short*)p;  p += (size_t)16 * 2048 * 256 * 2;
  unsigned short* kws = (unsigned short*)p;  p += (size_t)16 * 2048 * 256 * 2;
  unsigned char*  vp8 = (unsigned char*)p;   p += (size_t)16 * 1024 * 2048;
  char* dyn = p;
  const size_t fixed_bytes = (size_t)(dyn - (char*)d_ws);
  const size_t per_batch = (size_t)2048 * 2048 * 2 + (size_t)2048 * 2048;  // S + P
  int nb = 1;
  if      (ws_size >= fixed_bytes + 16 * per_batch) nb = 16;
  else if (ws_size >= fixed_bytes + 8  * per_batch) nb = 8;
  else if (ws_size >= fixed_bytes + 4  * per_batch) nb = 4;
  else if (ws_size >= fixed_bytes + 2  * per_batch) nb = 2;
  else nb = 1;
  unsigned short* Sp = (unsigned short*)dyn;
  unsigned char*  Pp = (unsigned char*)(dyn + (size_t)nb * 2048 * 2048 * 2);

  const int n8 = (16 * 2048 * 1024) / 8;
  cvt_bf16<<<2048, 256, 0, stream>>>(x, xb, n8);
  cvt_bf16<<<2048, 256, 0, stream>>>(y, yb, n8);
  tcvt<<<dim3(8, 32),  256, 0, stream>>>(Wq, Wqt, 1024, 256);
  tcvt<<<dim3(8, 32),  256, 0, stream>>>(Wk, Wkt, 1024, 256);
  tcvt<<<dim3(32, 32), 256, 0, stream>>>(Wv, Wvt, 1024, 1024);

  // q scaled by 1/sqrt(OUT_DIM) = 1/32
  proj_gemm<<<dim3(256, 2), 256, 0, stream>>>(xb, Wqt, qws, 256, 0.03125f);
  proj_gemm<<<dim3(256, 2), 256, 0, stream>>>(yb, Wkt, kws, 256, 1.0f);
  // V projection: 256^2 4-phase, fp8 packed epilogue (M=32768, N=1024, K=1024)
  gemm4p<16, 4, 2><<<512, 512, 0, stream>>>(
      yb, Wvt, 0, 0, 1024, 1024, (unsigned short*)vp8, 0, 1);

  for (int b0 = 0; b0 < 16; b0 += nb) {
    gemm4p<4, 8, 0><<<nb * 64, 512, 0, stream>>>(
        qws, kws, (size_t)2048 * 256, (size_t)2048 * 256, 256, 256,
        Sp, b0, nb);
    softmax_kernel<<<nb * 512, 256, 0, stream>>>(Sp, Pp);
    pvf8_kernel<<<nb * 64, 512, 0, stream>>>(Pp, vp8, x, out, b0, nb);
  }
}

// Round 15
// 460.275 us; speedup vs baseline: 1.7594x; 1.7594x over previous
//
#include <hip/hip_runtime.h>

typedef __attribute__((ext_vector_type(8))) short bf16x8;
typedef __attribute__((ext_vector_type(4))) short s16x4;
typedef __attribute__((ext_vector_type(4))) float f32x4;

#define MFMA16(a,b,c) __builtin_amdgcn_mfma_f32_16x16x32_bf16((a),(b),(c),0,0,0)

__device__ __forceinline__ unsigned short f2bf(float f) {
  unsigned int u = __float_as_uint(f);
  return (unsigned short)((u + 0x7fffu + ((u >> 16) & 1u)) >> 16);  // RNE
}
__device__ __forceinline__ float bf2f(unsigned short u) {
  return __uint_as_float(((unsigned int)u) << 16);
}

__device__ __forceinline__ void gload16(const void* g, void* l) {
  __builtin_amdgcn_global_load_lds((const __attribute__((address_space(1))) void*)g,
                                   (__attribute__((address_space(3))) void*)l, 16, 0, 0);
}

// ---- f32 -> bf16 bulk convert ----
__global__ __launch_bounds__(256) void cvt_bf16(const float* __restrict__ in,
                                                unsigned short* __restrict__ out, int n8) {
  for (int i = blockIdx.x * 256 + threadIdx.x; i < n8; i += gridDim.x * 256) {
    float4 a = ((const float4*)in)[2 * i];
    float4 b = ((const float4*)in)[2 * i + 1];
    s16x4 p0, p1;
    p0[0] = f2bf(a.x); p0[1] = f2bf(a.y); p0[2] = f2bf(a.z); p0[3] = f2bf(a.w);
    p1[0] = f2bf(b.x); p1[1] = f2bf(b.y); p1[2] = f2bf(b.z); p1[3] = f2bf(b.w);
    ((s16x4*)out)[2 * i] = p0;
    ((s16x4*)out)[2 * i + 1] = p1;
  }
}

// ---- W[K][N] f32 -> Wt[N][K] bf16 ----
__global__ __launch_bounds__(256) void tcvt(const float* __restrict__ W,
                                            unsigned short* __restrict__ Wt, int K, int N) {
  __shared__ float t[32][33];
  const int n0 = blockIdx.x * 32, k0 = blockIdx.y * 32;
  const int c = threadIdx.x & 31, r8 = threadIdx.x >> 5;
#pragma unroll
  for (int p = 0; p < 4; ++p) {
    int r = r8 + p * 8;
    t[r][c] = W[(size_t)(k0 + r) * N + n0 + c];
  }
  __syncthreads();
#pragma unroll
  for (int p = 0; p < 4; ++p) {
    int r = r8 + p * 8;
    Wt[(size_t)(n0 + r) * K + k0 + c] = f2bf(t[c][r]);
  }
}

// ---- projection GEMM (128x128, bf16 out): C = A[M,1024] @ Bt[N,1024]^T ----
__global__ __launch_bounds__(256) void proj_gemm(
    const unsigned short* __restrict__ A, const unsigned short* __restrict__ Bt,
    unsigned short* __restrict__ C, int N, float scale)
{
  __shared__ __align__(16) unsigned short As[2][4096];
  __shared__ __align__(16) unsigned short Bs[2][4096];
  const int tid = threadIdx.x, lane = tid & 63, w = tid >> 6;
  const int wr = w >> 1, wc = w & 1;
  const int lrow = lane & 15, lg = lane >> 4;
  const size_t bm = (size_t)blockIdx.x * 128;
  const size_t bn = (size_t)blockIdx.y * 128;
  const int rl = lane >> 2, cq = lane & 3;

  auto stage = [&](int kt, int buf) {
#pragma unroll
    for (int u = 0; u < 2; ++u) {
      int row = w * 32 + u * 16 + rl;
      gload16(A  + (bm + row) * 1024 + kt * 32 + cq * 8, &As[buf][(w * 32 + u * 16) * 32]);
      gload16(Bt + (bn + row) * 1024 + kt * 32 + cq * 8, &Bs[buf][(w * 32 + u * 16) * 32]);
    }
  };

  f32x4 acc[4][4] = {};
  stage(0, 0);
  __syncthreads();

  for (int kt = 0; kt < 32; ++kt) {
    const int cur = kt & 1;
    if (kt + 1 < 32) stage(kt + 1, cur ^ 1);
    bf16x8 af[4], bfr[4];
#pragma unroll
    for (int i = 0; i < 4; ++i)
      af[i] = *(const bf16x8*)&As[cur][(wr * 64 + i * 16 + lrow) * 32 + lg * 8];
#pragma unroll
    for (int j = 0; j < 4; ++j)
      bfr[j] = *(const bf16x8*)&Bs[cur][(wc * 64 + j * 16 + lrow) * 32 + lg * 8];
    __builtin_amdgcn_s_setprio(1);
#pragma unroll
    for (int i = 0; i < 4; ++i)
#pragma unroll
      for (int j = 0; j < 4; ++j)
        acc[i][j] = MFMA16(af[i], bfr[j], acc[i][j]);
    __builtin_amdgcn_s_setprio(0);
    __syncthreads();
  }

  const int orow0 = blockIdx.x * 128 + wr * 64;
  const int ocol0 = blockIdx.y * 128 + wc * 64;
#pragma unroll
  for (int i = 0; i < 4; ++i)
#pragma unroll
    for (int j = 0; j < 4; ++j) {
      int col = ocol0 + j * 16 + lrow;
#pragma unroll
      for (int r = 0; r < 4; ++r) {
        int row = orow0 + i * 16 + lg * 4 + r;
        C[(size_t)row * N + col] = f2bf(acc[i][j][r] * scale);
      }
    }
}

// ======================================================================
// 4-phase 256x256 bf16 GEMM (BK=64), cross-phase ds_read pipelining.
// MODE 0: bf16 C [nb][2048][2048] (sgemm).
// MODE 2: fp8 packed V: C8[b][eg=e/16][tw=m/64 in batch][e%16][m%64].
// ======================================================================
#define SBAR  do { __builtin_amdgcn_s_barrier(); __builtin_amdgcn_sched_barrier(0); } while (0)

template<int NT, int NTIL, int MODE>
__global__ __launch_bounds__(512) void gemm4p(
    const unsigned short* __restrict__ Aall, const unsigned short* __restrict__ Ball,
    size_t abatch, size_t bbatch, int lda, int ldb,
    unsigned short* __restrict__ Cb, int b0, int nb)
{
  __shared__ __align__(16) unsigned short lds[65536];  // 128 KB
  const int bid = blockIdx.x;
  const int bloc = bid % nb, tl = bid / nb;
  const int mtile = tl / NTIL, ntile = tl % NTIL;
  const int gb = b0 + bloc;
  const unsigned short* Ag = Aall + (MODE == 0 ? (size_t)gb : (size_t)bloc) * abatch
                                  + (size_t)mtile * 256 * lda;
  const unsigned short* Bg = Ball + (size_t)gb * bbatch + (size_t)ntile * 256 * ldb;

  const int tid = threadIdx.x, lane = tid & 63, w = tid >> 6;
  const int wm = w >> 2, wn = w & 3;
  const int lrow = lane & 15, lg = lane >> 4;
  char* lb = (char*)lds;

  auto stageU = [&](const unsigned short* G, int ld, int kofs, int ubyte) {
#pragma unroll
    for (int i = 0; i < 2; ++i) {
      int c = tid + 512 * i;
      int row = c >> 2, q = c & 3;
      int qs = q ^ ((row >> 1) & 3);
      gload16(G + (size_t)row * ld + kofs + qs * 8, lb + ubyte + c * 16);
    }
  };
  auto rdfrag = [&](int ubyte, int row) -> bf16x8 {
    return *(const bf16x8*)(lb + ubyte + row * 64 + ((lg ^ ((row >> 1) & 3)) << 4));
  };

  f32x4 acc[8][4] = {};
  bf16x8 afA[4], afB[4], bfrA[4], bfrB[4];

  stageU(Ag, lda, 0,  (0 * 2 + 0) * 16384);
  stageU(Bg, ldb, 0,  (1 * 2 + 0) * 16384);
  stageU(Ag, lda, 32, (2 * 2 + 0) * 16384);
  stageU(Bg, ldb, 32, (3 * 2 + 0) * 16384);
  stageU(Ag, lda, 64, (0 * 2 + 1) * 16384);
  stageU(Bg, ldb, 64, (1 * 2 + 1) * 16384);
  asm volatile("s_waitcnt vmcnt(8)" ::: "memory");
  SBAR;
#pragma unroll
  for (int i = 0; i < 4; ++i) afA[i] = rdfrag(0, wm * 128 + i * 16 + lrow);
#pragma unroll
  for (int nf = 0; nf < 4; ++nf) bfrA[nf] = rdfrag(2 * 16384, wn * 64 + nf * 16 + lrow);

  for (int T = 0; T < NT; ++T) {
    const int pc = T & 1, pn = (T + 1) & 1;
    const int a1b = (2 * 2 + pc) * 16384, b1b = (3 * 2 + pc) * 16384;
    const int a0b = (0 * 2 + pc) * 16384;
    const int t1 = (T + 1 < NT) ? T + 1 : 0;
    const int t2 = (T + 2 < NT) ? T + 2 : 0;

#pragma unroll
    for (int i = 0; i < 4; ++i) afB[i] = rdfrag(a0b, wm * 128 + (i + 4) * 16 + lrow);
    stageU(Ag, lda, t1 * 64 + 32, (2 * 2 + pn) * 16384);
    asm volatile("s_waitcnt lgkmcnt(4)" ::: "memory");
    __builtin_amdgcn_sched_barrier(0);
    __builtin_amdgcn_s_setprio(1);
#pragma unroll
    for (int mf = 0; mf < 4; ++mf)
#pragma unroll
      for (int nf = 0; nf < 4; ++nf)
        acc[mf][nf] = MFMA16(afA[mf], bfrA[nf], acc[mf][nf]);
    __builtin_amdgcn_s_setprio(0);
    asm volatile("s_waitcnt vmcnt(6)" ::: "memory");
    SBAR;

#pragma unroll
    for (int i = 0; i < 4; ++i) afA[i] = rdfrag(a1b, wm * 128 + i * 16 + lrow);
#pragma unroll
    for (int nf = 0; nf < 4; ++nf) bfrB[nf] = rdfrag(b1b, wn * 64 + nf * 16 + lrow);
    stageU(Bg, ldb, t1 * 64 + 32, (3 * 2 + pn) * 16384);
    asm volatile("s_waitcnt lgkmcnt(8)" ::: "memory");
    __builtin_amdgcn_sched_barrier(0);
    __builtin_amdgcn_s_setprio(1);
#pragma unroll
    for (int mf = 0; mf < 4; ++mf)
#pragma unroll
      for (int nf = 0; nf < 4; ++nf)
        acc[mf + 4][nf] = MFMA16(afB[mf], bfrA[nf], acc[mf + 4][nf]);
    __builtin_amdgcn_s_setprio(0);
    SBAR;

#pragma unroll
    for (int i = 0; i < 4; ++i) afB[i] = rdfrag(a1b, wm * 128 + (i + 4) * 16 + lrow);
    stageU(Ag, lda, t2 * 64, (0 * 2 + pc) * 16384);
    asm volatile("s_waitcnt lgkmcnt(4)" ::: "memory");
    __builtin_amdgcn_sched_barrier(0);
    __builtin_amdgcn_s_setprio(1);
#pragma unroll
    for (int mf = 0; mf < 4; ++mf)
#pragma unroll
      for (int nf = 0; nf < 4; ++nf)
        acc[mf][nf] = MFMA16(afA[mf], bfrB[nf], acc[mf][nf]);
    __builtin_amdgcn_s_setprio(0);
    asm volatile("s_waitcnt vmcnt(6)" ::: "memory");
    SBAR;

#pragma unroll
    for (int i = 0; i < 4; ++i) afA[i] = rdfrag((0 * 2 + pn) * 16384, wm * 128 + i * 16 + lrow);
#pragma unroll
    for (int nf = 0; nf < 4; ++nf) bfrA[nf] = rdfrag((1 * 2 + pn) * 16384, wn * 64 + nf * 16 + lrow);
    stageU(Bg, ldb, t2 * 64, (1 * 2 + pc) * 16384);
    asm volatile("s_waitcnt lgkmcnt(8)" ::: "memory");
    __builtin_amdgcn_sched_barrier(0);
    __builtin_amdgcn_s_setprio(1);
#pragma unroll
    for (int mf = 0; mf < 4; ++mf)
#pragma unroll
      for (int nf = 0; nf < 4; ++nf)
        acc[mf + 4][nf] = MFMA16(afB[mf], bfrB[nf], acc[mf + 4][nf]);
    __builtin_amdgcn_s_setprio(0);
    SBAR;
  }

  if (MODE == 0) {
    unsigned short* Cp = Cb + (size_t)bloc * 2048 * 2048;
#pragma unroll
    for (int mf = 0; mf < 8; ++mf)
#pragma unroll
      for (int r = 0; r < 4; ++r) {
        int row = mtile * 256 + wm * 128 + mf * 16 + lg * 4 + r;
#pragma unroll
        for (int nf = 0; nf < 4; ++nf) {
          int col = ntile * 256 + wn * 64 + nf * 16 + lrow;
          Cp[(size_t)row * 2048 + col] = f2bf(acc[mf][nf][r]);
        }
      }
  } else {
    // packed fp8 V: [b][eg][tw][e%16][t%64]
    unsigned char* C8 = (unsigned char*)Cb;
#pragma unroll
    for (int mf = 0; mf < 8; ++mf) {
      int m0 = mtile * 256 + wm * 128 + mf * 16 + lg * 4;  // 4 consecutive t
      int bb = m0 >> 11, t = m0 & 2047;
      int tw = t >> 6, t64 = t & 63;
#pragma unroll
      for (int nf = 0; nf < 4; ++nf) {
        int e = ntile * 256 + wn * 64 + nf * 16 + lrow;    // e%16 == lrow
        int eg = e >> 4;
        int pk = 0;
        pk = __builtin_amdgcn_cvt_pk_fp8_f32(acc[mf][nf][0], acc[mf][nf][1], pk, false);
        pk = __builtin_amdgcn_cvt_pk_fp8_f32(acc[mf][nf][2], acc[mf][nf][3], pk, true);
        *(unsigned int*)(C8 + (size_t)bb * 2097152
                            + ((size_t)(eg * 32 + tw)) * 1024 + lrow * 64 + t64)
            = (unsigned int)pk;
      }
    }
  }
}

// ---- softmax: read S bf16, write P fp8 e4m3 scaled x64. 1 wave / row ----
__global__ __launch_bounds__(256) void softmax_kernel(
    const unsigned short* __restrict__ Sp, unsigned char* __restrict__ Pp) {
  const int row = blockIdx.x * 4 + (threadIdx.x >> 6);
  const int lane = threadIdx.x & 63;
  const unsigned short* rp = Sp + (size_t)row * 2048;
  bf16x8 raw[4];
#pragma unroll
  for (int c = 0; c < 4; ++c) raw[c] = *(const bf16x8*)(rp + c * 512 + lane * 8);
  float v[32];
#pragma unroll
  for (int c = 0; c < 4; ++c)
#pragma unroll
    for (int j = 0; j < 8; ++j) v[c * 8 + j] = bf2f((unsigned short)raw[c][j]);
  float mx = v[0];
#pragma unroll
  for (int j = 1; j < 32; ++j) mx = fmaxf(mx, v[j]);
  mx = fmaxf(mx, __shfl_xor(mx, 1));
  mx = fmaxf(mx, __shfl_xor(mx, 2));
  mx = fmaxf(mx, __shfl_xor(mx, 4));
  mx = fmaxf(mx, __shfl_xor(mx, 8));
  mx = fmaxf(mx, __shfl_xor(mx, 16));
  mx = fmaxf(mx, __shfl_xor(mx, 32));
  float sum = 0.f;
#pragma unroll
  for (int j = 0; j < 32; ++j) { v[j] = __expf(v[j] - mx); sum += v[j]; }
  sum += __shfl_xor(sum, 1);
  sum += __shfl_xor(sum, 2);
  sum += __shfl_xor(sum, 4);
  sum += __shfl_xor(sum, 8);
  sum += __shfl_xor(sum, 16);
  sum += __shfl_xor(sum, 32);
  const float scale = 64.0f / sum;
  unsigned char* rp8 = Pp + (size_t)row * 2048;
#pragma unroll
  for (int c = 0; c < 4; ++c) {
    int lo = 0, hi = 0;
    lo = __builtin_amdgcn_cvt_pk_fp8_f32(v[c * 8 + 0] * scale, v[c * 8 + 1] * scale, lo, false);
    lo = __builtin_amdgcn_cvt_pk_fp8_f32(v[c * 8 + 2] * scale, v[c * 8 + 3] * scale, lo, true);
    hi = __builtin_amdgcn_cvt_pk_fp8_f32(v[c * 8 + 4] * scale, v[c * 8 + 5] * scale, hi, false);
    hi = __builtin_amdgcn_cvt_pk_fp8_f32(v[c * 8 + 6] * scale, v[c * 8 + 7] * scale, hi, true);
    uint2 o; o.x = (unsigned int)lo; o.y = (unsigned int)hi;
    *(uint2*)(rp8 + c * 512 + lane * 8) = o;
  }
}

// ======================================================================
// fp8 PV GEMM, 256x128 tile, 2 blocks/CU (round-13 verified config):
// A (P) staged in LDS (4 x 16KB, stage 3 ahead), B (V) direct from packed
// global [eg][tw][16][64] (L2-hot, XCD-pinned). acc[8][2]=64 regs.
// NOTE: do NOT set min-waves in launch_bounds — capping the allocator
// below the ~52-VGPR live set causes 1GB of scratch spills (round 14).
// ======================================================================
__global__ __launch_bounds__(512) void pvf8_kernel(
    const unsigned char* __restrict__ Pp,   // [nb][2048][2048] fp8 (x64)
    const unsigned char* __restrict__ Vp,   // [16] packed [64][32][16][64] fp8
    const float* __restrict__ X, float* __restrict__ Out,
    int b0, int nb)
{
  __shared__ __align__(16) unsigned char lds[4][16384];
  const int bloc = blockIdx.x % nb, tl = blockIdx.x / nb;
  const int mtile = tl >> 3, ntile = tl & 7;   // 8 mtiles x 8 ntiles
  const int gb = b0 + bloc;
  const unsigned char* Ag = Pp + (size_t)bloc * 4194304 + (size_t)mtile * 256 * 2048;
  const unsigned char* Vb = Vp + (size_t)gb * 2097152;
  const int NT = 32;
  const int tid = threadIdx.x, lane = tid & 63, w = tid >> 6;
  const int wm = w >> 2, wn = w & 3;           // 2 x 4 waves over 256 x 128
  const int lrow = lane & 15, lg = lane >> 4;

  auto stageA = [&](int jt) {
    unsigned char* dst = lds[jt & 3];
#pragma unroll
    for (int i = 0; i < 2; ++i) {
      int c = tid + 512 * i; int row = c >> 2; int q = (c & 3) ^ ((row >> 1) & 3);
      gload16(Ag + (size_t)row * 2048 + jt * 64 + q * 16, dst + c * 16);
    }
  };

  f32x4 acc[8][2] = {};
  stageA(0); stageA(1); stageA(2);
  asm volatile("s_waitcnt vmcnt(4)" ::: "memory");   // A(0) landed

  for (int jt = 0; jt < NT; ++jt) {
    __builtin_amdgcn_s_barrier();
    // B direct (packed V, 1KB/wave-frag, L2-hot) — issued BEFORE the stage
    long2 bv[2];
#pragma unroll
    for (int nf = 0; nf < 2; ++nf) {
      int eg = ntile * 8 + wn * 2 + nf;
      bv[nf] = *(const long2*)(Vb + ((size_t)(eg * 32 + jt)) * 1024 + lrow * 64 + lg * 16);
    }
    if (jt + 3 < NT) stageA(jt + 3);   // slot (jt-1): readers drained pre-barrier
    const unsigned char* Ab = lds[jt & 3];
    // first half: rows 0..63
    {
      long2 av[4];
#pragma unroll
      for (int mf = 0; mf < 4; ++mf) {
        int row = wm * 128 + mf * 16 + lrow;
        av[mf] = *(const long2*)(Ab + row * 64 + ((lg ^ ((row >> 1) & 3)) << 4));
      }
      __builtin_amdgcn_s_setprio(1);
#pragma unroll
      for (int mf = 0; mf < 4; ++mf)
#pragma unroll
        for (int nf = 0; nf < 2; ++nf) {
          acc[mf][nf] = __builtin_amdgcn_mfma_f32_16x16x32_fp8_fp8(av[mf].x, bv[nf].x, acc[mf][nf], 0, 0, 0);
          acc[mf][nf] = __builtin_amdgcn_mfma_f32_16x16x32_fp8_fp8(av[mf].y, bv[nf].y, acc[mf][nf], 0, 0, 0);
        }
      __builtin_amdgcn_s_setprio(0);
    }
    // second half: rows 64..127
    {
      long2 av[4];
#pragma unroll
      for (int mf = 0; mf < 4; ++mf) {
        int row = wm * 128 + (mf + 4) * 16 + lrow;
        av[mf] = *(const long2*)(Ab + row * 64 + ((lg ^ ((row >> 1) & 3)) << 4));
      }
      __builtin_amdgcn_s_setprio(1);
#pragma unroll
      for (int mf = 0; mf < 4; ++mf)
#pragma unroll
        for (int nf = 0; nf < 2; ++nf) {
          acc[mf + 4][nf] = __builtin_amdgcn_mfma_f32_16x16x32_fp8_fp8(av[mf].x, bv[nf].x, acc[mf + 4][nf], 0, 0, 0);
          acc[mf + 4][nf] = __builtin_amdgcn_mfma_f32_16x16x32_fp8_fp8(av[mf].y, bv[nf].y, acc[mf + 4][nf], 0, 0, 0);
        }
      __builtin_amdgcn_s_setprio(0);
    }
  }

#pragma unroll
  for (int mf = 0; mf < 8; ++mf)
#pragma unroll
    for (int r = 0; r < 4; ++r) {
      int row = mtile * 256 + wm * 128 + mf * 16 + lg * 4 + r;
      const float* xr = X   + ((size_t)gb * 2048 + row) * 1024;
      float*      orp = Out + ((size_t)gb * 2048 + row) * 1024;
#pragma unroll
      for (int nf = 0; nf < 2; ++nf) {
        int col = ntile * 128 + wn * 32 + nf * 16 + lrow;
        orp[col] = acc[mf][nf][r] * 0.015625f + xr[col];   // /64 un-scale
      }
    }
}

extern "C" void kernel_launch(void* const* d_in, const int* in_sizes, int n_in,
                              void* d_out, int out_size, void* d_ws, size_t ws_size,
                              hipStream_t stream) {
  (void)in_sizes; (void)n_in; (void)out_size;
  const float* x  = (const float*)d_in[0];
  const float* y  = (const float*)d_in[1];
  const float* Wq = (const float*)d_in[2];
  const float* Wk = (const float*)d_in[3];
  const float* Wv = (const float*)d_in[4];
  float* out = (float*)d_out;

  // bf16 copies of x,y live in d_out during projections (overwritten later)
  unsigned short* xb = (unsigned short*)d_out;
  unsigned short* yb = xb + (size_t)16 * 2048 * 1024;

  // ws: Wqt | Wkt | Wvt (bf16) | q | k (bf16) | Vp (fp8 packed) | S (bf16) | P (fp8)
  char* p = (char*)d_ws;
  unsigned short* Wqt = (unsigned short*)p;  p += (size_t)256 * 1024 * 2;
  unsigned short* Wkt = (unsigned short*)p;  p += (size_t)256 * 1024 * 2;
  unsigned short* Wvt = (unsigned short*)p;  p += (size_t)1024 * 1024 * 2;
  unsigned short* qws = (unsigned short*)p;  p += (size_t)16 * 2048 * 256 * 2;
  unsigned short* kws = (unsigned short*)p;  p += (size_t)16 * 2048 * 256 * 2;
  unsigned char*  vp8 = (unsigned char*)p;   p += (size_t)16 * 1024 * 2048;
  char* dyn = p;
  const size_t fixed_bytes = (size_t)(dyn - (char*)d_ws);
  const size_t per_batch = (size_t)2048 * 2048 * 2 + (size_t)2048 * 2048;  // S + P
  int nb = 1;
  if      (ws_size >= fixed_bytes + 16 * per_batch) nb = 16;
  else if (ws_size >= fixed_bytes + 8  * per_batch) nb = 8;
  else if (ws_size >= fixed_bytes + 4  * per_batch) nb = 4;
  else if (ws_size >= fixed_bytes + 2  * per_batch) nb = 2;
  else nb = 1;
  unsigned short* Sp = (unsigned short*)dyn;
  unsigned char*  Pp = (unsigned char*)(dyn + (size_t)nb * 2048 * 2048 * 2);

  const int n8 = (16 * 2048 * 1024) / 8;
  cvt_bf16<<<2048, 256, 0, stream>>>(x, xb, n8);
  cvt_bf16<<<2048, 256, 0, stream>>>(y, yb, n8);
  tcvt<<<dim3(8, 32),  256, 0, stream>>>(Wq, Wqt, 1024, 256);
  tcvt<<<dim3(8, 32),  256, 0, stream>>>(Wk, Wkt, 1024, 256);
  tcvt<<<dim3(32, 32), 256, 0, stream>>>(Wv, Wvt, 1024, 1024);

  // q scaled by 1/sqrt(OUT_DIM) = 1/32
  proj_gemm<<<dim3(256, 2), 256, 0, stream>>>(xb, Wqt, qws, 256, 0.03125f);
  proj_gemm<<<dim3(256, 2), 256, 0, stream>>>(yb, Wkt, kws, 256, 1.0f);
  // V projection: 256^2 4-phase, fp8 packed epilogue (M=32768, N=1024, K=1024)
  gemm4p<16, 4, 2><<<512, 512, 0, stream>>>(
      yb, Wvt, 0, 0, 1024, 1024, (unsigned short*)vp8, 0, 1);

  for (int b0 = 0; b0 < 16; b0 += nb) {
    gemm4p<4, 8, 0><<<nb * 64, 512, 0, stream>>>(
        qws, kws, (size_t)2048 * 256, (size_t)2048 * 256, 256, 256,
        Sp, b0, nb);
    softmax_kernel<<<nb * 512, 256, 0, stream>>>(Sp, Pp);
    pvf8_kernel<<<nb * 64, 512, 0, stream>>>(Pp, vp8, x, out, b0, nb);
  }
}

// Round 16
// 430.007 us; speedup vs baseline: 1.8832x; 1.0704x over previous
//
#include <hip/hip_runtime.h>

typedef __attribute__((ext_vector_type(8))) short bf16x8;
typedef __attribute__((ext_vector_type(4))) short s16x4;
typedef __attribute__((ext_vector_type(4))) float f32x4;

#define MFMA16(a,b,c) __builtin_amdgcn_mfma_f32_16x16x32_bf16((a),(b),(c),0,0,0)

__device__ __forceinline__ unsigned short f2bf(float f) {
  unsigned int u = __float_as_uint(f);
  return (unsigned short)((u + 0x7fffu + ((u >> 16) & 1u)) >> 16);  // RNE
}
__device__ __forceinline__ float bf2f(unsigned short u) {
  return __uint_as_float(((unsigned int)u) << 16);
}

__device__ __forceinline__ void gload16(const void* g, void* l) {
  __builtin_amdgcn_global_load_lds((const __attribute__((address_space(1))) void*)g,
                                   (__attribute__((address_space(3))) void*)l, 16, 0, 0);
}

// ---- f32 -> bf16 bulk convert ----
__global__ __launch_bounds__(256) void cvt_bf16(const float* __restrict__ in,
                                                unsigned short* __restrict__ out, int n8) {
  for (int i = blockIdx.x * 256 + threadIdx.x; i < n8; i += gridDim.x * 256) {
    float4 a = ((const float4*)in)[2 * i];
    float4 b = ((const float4*)in)[2 * i + 1];
    s16x4 p0, p1;
    p0[0] = f2bf(a.x); p0[1] = f2bf(a.y); p0[2] = f2bf(a.z); p0[3] = f2bf(a.w);
    p1[0] = f2bf(b.x); p1[1] = f2bf(b.y); p1[2] = f2bf(b.z); p1[3] = f2bf(b.w);
    ((s16x4*)out)[2 * i] = p0;
    ((s16x4*)out)[2 * i + 1] = p1;
  }
}

// ---- W[K][N] f32 -> Wt[N][K] bf16 ----
__global__ __launch_bounds__(256) void tcvt(const float* __restrict__ W,
                                            unsigned short* __restrict__ Wt, int K, int N) {
  __shared__ float t[32][33];
  const int n0 = blockIdx.x * 32, k0 = blockIdx.y * 32;
  const int c = threadIdx.x & 31, r8 = threadIdx.x >> 5;
#pragma unroll
  for (int p = 0; p < 4; ++p) {
    int r = r8 + p * 8;
    t[r][c] = W[(size_t)(k0 + r) * N + n0 + c];
  }
  __syncthreads();
#pragma unroll
  for (int p = 0; p < 4; ++p) {
    int r = r8 + p * 8;
    Wt[(size_t)(n0 + r) * K + k0 + c] = f2bf(t[c][r]);
  }
}

// ======================================================================
// 4-phase 256x256 bf16 GEMM (BK=64), cross-phase ds_read pipelining.
// MODE 0: bf16 C [nb][2048][2048] (sgemm).
// MODE 2: fp8 packed V: C8[b][eg=e/16][tw=m/64 in batch][e%16][m%64].
// MODE 3: q/k projection pair: bloc=0 -> q (scale 1/32), bloc=1 -> k;
//         C row-major ld=256 at Cb + bloc*16*2048*256.
// ======================================================================
#define SBAR  do { __builtin_amdgcn_s_barrier(); __builtin_amdgcn_sched_barrier(0); } while (0)

template<int NT, int NTIL, int MODE>
__global__ __launch_bounds__(512) void gemm4p(
    const unsigned short* __restrict__ Aall, const unsigned short* __restrict__ Ball,
    size_t abatch, size_t bbatch, int lda, int ldb,
    unsigned short* __restrict__ Cb, int b0, int nb)
{
  __shared__ __align__(16) unsigned short lds[65536];  // 128 KB
  const int bid = blockIdx.x;
  const int bloc = bid % nb, tl = bid / nb;
  const int mtile = tl / NTIL, ntile = tl % NTIL;
  const int gb = b0 + bloc;
  const unsigned short* Ag = Aall + (MODE == 0 ? (size_t)gb : (size_t)bloc) * abatch
                                  + (size_t)mtile * 256 * lda;
  const unsigned short* Bg = Ball + (size_t)gb * bbatch + (size_t)ntile * 256 * ldb;

  const int tid = threadIdx.x, lane = tid & 63, w = tid >> 6;
  const int wm = w >> 2, wn = w & 3;
  const int lrow = lane & 15, lg = lane >> 4;
  char* lb = (char*)lds;

  auto stageU = [&](const unsigned short* G, int ld, int kofs, int ubyte) {
#pragma unroll
    for (int i = 0; i < 2; ++i) {
      int c = tid + 512 * i;
      int row = c >> 2, q = c & 3;
      int qs = q ^ ((row >> 1) & 3);
      gload16(G + (size_t)row * ld + kofs + qs * 8, lb + ubyte + c * 16);
    }
  };
  auto rdfrag = [&](int ubyte, int row) -> bf16x8 {
    return *(const bf16x8*)(lb + ubyte + row * 64 + ((lg ^ ((row >> 1) & 3)) << 4));
  };

  f32x4 acc[8][4] = {};
  bf16x8 afA[4], afB[4], bfrA[4], bfrB[4];

  stageU(Ag, lda, 0,  (0 * 2 + 0) * 16384);
  stageU(Bg, ldb, 0,  (1 * 2 + 0) * 16384);
  stageU(Ag, lda, 32, (2 * 2 + 0) * 16384);
  stageU(Bg, ldb, 32, (3 * 2 + 0) * 16384);
  stageU(Ag, lda, 64, (0 * 2 + 1) * 16384);
  stageU(Bg, ldb, 64, (1 * 2 + 1) * 16384);
  asm volatile("s_waitcnt vmcnt(8)" ::: "memory");
  SBAR;
#pragma unroll
  for (int i = 0; i < 4; ++i) afA[i] = rdfrag(0, wm * 128 + i * 16 + lrow);
#pragma unroll
  for (int nf = 0; nf < 4; ++nf) bfrA[nf] = rdfrag(2 * 16384, wn * 64 + nf * 16 + lrow);

  for (int T = 0; T < NT; ++T) {
    const int pc = T & 1, pn = (T + 1) & 1;
    const int a1b = (2 * 2 + pc) * 16384, b1b = (3 * 2 + pc) * 16384;
    const int a0b = (0 * 2 + pc) * 16384;
    const int t1 = (T + 1 < NT) ? T + 1 : 0;
    const int t2 = (T + 2 < NT) ? T + 2 : 0;

#pragma unroll
    for (int i = 0; i < 4; ++i) afB[i] = rdfrag(a0b, wm * 128 + (i + 4) * 16 + lrow);
    stageU(Ag, lda, t1 * 64 + 32, (2 * 2 + pn) * 16384);
    asm volatile("s_waitcnt lgkmcnt(4)" ::: "memory");
    __builtin_amdgcn_sched_barrier(0);
    __builtin_amdgcn_s_setprio(1);
#pragma unroll
    for (int mf = 0; mf < 4; ++mf)
#pragma unroll
      for (int nf = 0; nf < 4; ++nf)
        acc[mf][nf] = MFMA16(afA[mf], bfrA[nf], acc[mf][nf]);
    __builtin_amdgcn_s_setprio(0);
    asm volatile("s_waitcnt vmcnt(6)" ::: "memory");
    SBAR;

#pragma unroll
    for (int i = 0; i < 4; ++i) afA[i] = rdfrag(a1b, wm * 128 + i * 16 + lrow);
#pragma unroll
    for (int nf = 0; nf < 4; ++nf) bfrB[nf] = rdfrag(b1b, wn * 64 + nf * 16 + lrow);
    stageU(Bg, ldb, t1 * 64 + 32, (3 * 2 + pn) * 16384);
    asm volatile("s_waitcnt lgkmcnt(8)" ::: "memory");
    __builtin_amdgcn_sched_barrier(0);
    __builtin_amdgcn_s_setprio(1);
#pragma unroll
    for (int mf = 0; mf < 4; ++mf)
#pragma unroll
      for (int nf = 0; nf < 4; ++nf)
        acc[mf + 4][nf] = MFMA16(afB[mf], bfrA[nf], acc[mf + 4][nf]);
    __builtin_amdgcn_s_setprio(0);
    SBAR;

#pragma unroll
    for (int i = 0; i < 4; ++i) afB[i] = rdfrag(a1b, wm * 128 + (i + 4) * 16 + lrow);
    stageU(Ag, lda, t2 * 64, (0 * 2 + pc) * 16384);
    asm volatile("s_waitcnt lgkmcnt(4)" ::: "memory");
    __builtin_amdgcn_sched_barrier(0);
    __builtin_amdgcn_s_setprio(1);
#pragma unroll
    for (int mf = 0; mf < 4; ++mf)
#pragma unroll
      for (int nf = 0; nf < 4; ++nf)
        acc[mf][nf] = MFMA16(afA[mf], bfrB[nf], acc[mf][nf]);
    __builtin_amdgcn_s_setprio(0);
    asm volatile("s_waitcnt vmcnt(6)" ::: "memory");
    SBAR;

#pragma unroll
    for (int i = 0; i < 4; ++i) afA[i] = rdfrag((0 * 2 + pn) * 16384, wm * 128 + i * 16 + lrow);
#pragma unroll
    for (int nf = 0; nf < 4; ++nf) bfrA[nf] = rdfrag((1 * 2 + pn) * 16384, wn * 64 + nf * 16 + lrow);
    stageU(Bg, ldb, t2 * 64, (1 * 2 + pc) * 16384);
    asm volatile("s_waitcnt lgkmcnt(8)" ::: "memory");
    __builtin_amdgcn_sched_barrier(0);
    __builtin_amdgcn_s_setprio(1);
#pragma unroll
    for (int mf = 0; mf < 4; ++mf)
#pragma unroll
      for (int nf = 0; nf < 4; ++nf)
        acc[mf + 4][nf] = MFMA16(afB[mf], bfrB[nf], acc[mf + 4][nf]);
    __builtin_amdgcn_s_setprio(0);
    SBAR;
  }

  if (MODE == 0) {
    unsigned short* Cp = Cb + (size_t)bloc * 2048 * 2048;
#pragma unroll
    for (int mf = 0; mf < 8; ++mf)
#pragma unroll
      for (int r = 0; r < 4; ++r) {
        int row = mtile * 256 + wm * 128 + mf * 16 + lg * 4 + r;
#pragma unroll
        for (int nf = 0; nf < 4; ++nf) {
          int col = ntile * 256 + wn * 64 + nf * 16 + lrow;
          Cp[(size_t)row * 2048 + col] = f2bf(acc[mf][nf][r]);
        }
      }
  } else if (MODE == 2) {
    // packed fp8 V: [b][eg][tw][e%16][t%64]
    unsigned char* C8 = (unsigned char*)Cb;
#pragma unroll
    for (int mf = 0; mf < 8; ++mf) {
      int m0 = mtile * 256 + wm * 128 + mf * 16 + lg * 4;  // 4 consecutive t
      int bb = m0 >> 11, t = m0 & 2047;
      int tw = t >> 6, t64 = t & 63;
#pragma unroll
      for (int nf = 0; nf < 4; ++nf) {
        int e = ntile * 256 + wn * 64 + nf * 16 + lrow;    // e%16 == lrow
        int eg = e >> 4;
        int pk = 0;
        pk = __builtin_amdgcn_cvt_pk_fp8_f32(acc[mf][nf][0], acc[mf][nf][1], pk, false);
        pk = __builtin_amdgcn_cvt_pk_fp8_f32(acc[mf][nf][2], acc[mf][nf][3], pk, true);
        *(unsigned int*)(C8 + (size_t)bb * 2097152
                            + ((size_t)(eg * 32 + tw)) * 1024 + lrow * 64 + t64)
            = (unsigned int)pk;
      }
    }
  } else {
    // MODE 3: q/k pair; bloc 0 = q (scale 1/32), bloc 1 = k; ld = 256
    unsigned short* Cp = Cb + (size_t)bloc * 16 * 2048 * 256;
    const float scale = (bloc == 0) ? 0.03125f : 1.0f;
#pragma unroll
    for (int mf = 0; mf < 8; ++mf)
#pragma unroll
      for (int r = 0; r < 4; ++r) {
        int row = mtile * 256 + wm * 128 + mf * 16 + lg * 4 + r;
#pragma unroll
        for (int nf = 0; nf < 4; ++nf) {
          int col = wn * 64 + nf * 16 + lrow;
          Cp[(size_t)row * 256 + col] = f2bf(acc[mf][nf][r] * scale);
        }
      }
  }
}

// ---- softmax: read S bf16, write P fp8 e4m3 scaled x64. 1 wave / row ----
__global__ __launch_bounds__(256) void softmax_kernel(
    const unsigned short* __restrict__ Sp, unsigned char* __restrict__ Pp) {
  const int row = blockIdx.x * 4 + (threadIdx.x >> 6);
  const int lane = threadIdx.x & 63;
  const unsigned short* rp = Sp + (size_t)row * 2048;
  bf16x8 raw[4];
#pragma unroll
  for (int c = 0; c < 4; ++c) raw[c] = *(const bf16x8*)(rp + c * 512 + lane * 8);
  float v[32];
#pragma unroll
  for (int c = 0; c < 4; ++c)
#pragma unroll
    for (int j = 0; j < 8; ++j) v[c * 8 + j] = bf2f((unsigned short)raw[c][j]);
  float mx = v[0];
#pragma unroll
  for (int j = 1; j < 32; ++j) mx = fmaxf(mx, v[j]);
  mx = fmaxf(mx, __shfl_xor(mx, 1));
  mx = fmaxf(mx, __shfl_xor(mx, 2));
  mx = fmaxf(mx, __shfl_xor(mx, 4));
  mx = fmaxf(mx, __shfl_xor(mx, 8));
  mx = fmaxf(mx, __shfl_xor(mx, 16));
  mx = fmaxf(mx, __shfl_xor(mx, 32));
  float sum = 0.f;
#pragma unroll
  for (int j = 0; j < 32; ++j) { v[j] = __expf(v[j] - mx); sum += v[j]; }
  sum += __shfl_xor(sum, 1);
  sum += __shfl_xor(sum, 2);
  sum += __shfl_xor(sum, 4);
  sum += __shfl_xor(sum, 8);
  sum += __shfl_xor(sum, 16);
  sum += __shfl_xor(sum, 32);
  const float scale = 64.0f / sum;
  unsigned char* rp8 = Pp + (size_t)row * 2048;
#pragma unroll
  for (int c = 0; c < 4; ++c) {
    int lo = 0, hi = 0;
    lo = __builtin_amdgcn_cvt_pk_fp8_f32(v[c * 8 + 0] * scale, v[c * 8 + 1] * scale, lo, false);
    lo = __builtin_amdgcn_cvt_pk_fp8_f32(v[c * 8 + 2] * scale, v[c * 8 + 3] * scale, lo, true);
    hi = __builtin_amdgcn_cvt_pk_fp8_f32(v[c * 8 + 4] * scale, v[c * 8 + 5] * scale, hi, false);
    hi = __builtin_amdgcn_cvt_pk_fp8_f32(v[c * 8 + 6] * scale, v[c * 8 + 7] * scale, hi, true);
    uint2 o; o.x = (unsigned int)lo; o.y = (unsigned int)hi;
    *(uint2*)(rp8 + c * 512 + lane * 8) = o;
  }
}

// ======================================================================
// fp8 PV GEMM, 256x128 tile, 2 blocks/CU: A (P) staged in LDS (4 x 16KB,
// stage 3 ahead), B (V) direct from packed global, DOUBLE-BUFFERED in
// registers (bv(jt+1) loaded during jt's MFMA; the bvc=bvn copy puts the
// vmcnt wait after the MFMA cluster). acc[8][2]=64 AGPR + ~60 VGPR.
// NOTE: no min-waves in launch_bounds (round-14 spill lesson).
// ======================================================================
__global__ __launch_bounds__(512) void pvf8_kernel(
    const unsigned char* __restrict__ Pp,   // [nb][2048][2048] fp8 (x64)
    const unsigned char* __restrict__ Vp,   // [16] packed [64][32][16][64] fp8
    const float* __restrict__ X, float* __restrict__ Out,
    int b0, int nb)
{
  __shared__ __align__(16) unsigned char lds[4][16384];
  const int bloc = blockIdx.x % nb, tl = blockIdx.x / nb;
  const int mtile = tl >> 3, ntile = tl & 7;   // 8 mtiles x 8 ntiles
  const int gb = b0 + bloc;
  const unsigned char* Ag = Pp + (size_t)bloc * 4194304 + (size_t)mtile * 256 * 2048;
  const unsigned char* Vb = Vp + (size_t)gb * 2097152;
  const int NT = 32;
  const int tid = threadIdx.x, lane = tid & 63, w = tid >> 6;
  const int wm = w >> 2, wn = w & 3;           // 2 x 4 waves over 256 x 128
  const int lrow = lane & 15, lg = lane >> 4;

  auto stageA = [&](int jt) {
    unsigned char* dst = lds[jt & 3];
#pragma unroll
    for (int i = 0; i < 2; ++i) {
      int c = tid + 512 * i; int row = c >> 2; int q = (c & 3) ^ ((row >> 1) & 3);
      gload16(Ag + (size_t)row * 2048 + jt * 64 + q * 16, dst + c * 16);
    }
  };
  auto loadB = [&](int jt, long2* bv) {
#pragma unroll
    for (int nf = 0; nf < 2; ++nf) {
      int eg = ntile * 8 + wn * 2 + nf;
      bv[nf] = *(const long2*)(Vb + ((size_t)(eg * 32 + jt)) * 1024 + lrow * 64 + lg * 16);
    }
  };

  f32x4 acc[8][2] = {};
  stageA(0); stageA(1); stageA(2);
  long2 bvc[2];
  loadB(0, bvc);
  asm volatile("s_waitcnt vmcnt(6)" ::: "memory");   // stageA(0) drained
  __builtin_amdgcn_sched_barrier(0);

  for (int jt = 0; jt < NT; ++jt) {
    __builtin_amdgcn_s_barrier();
    if (jt + 3 < NT) stageA(jt + 3);   // slot (jt-1): readers drained pre-barrier
    long2 bvn[2];
    loadB(jt + 1 < NT ? jt + 1 : 0, bvn);   // overlaps with this jt's MFMA
    const unsigned char* Ab = lds[jt & 3];
    // first half: rows 0..63
    {
      long2 av[4];
#pragma unroll
      for (int mf = 0; mf < 4; ++mf) {
        int row = wm * 128 + mf * 16 + lrow;
        av[mf] = *(const long2*)(Ab + row * 64 + ((lg ^ ((row >> 1) & 3)) << 4));
      }
      __builtin_amdgcn_s_setprio(1);
#pragma unroll
      for (int mf = 0; mf < 4; ++mf)
#pragma unroll
        for (int nf = 0; nf < 2; ++nf) {
          acc[mf][nf] = __builtin_amdgcn_mfma_f32_16x16x32_fp8_fp8(av[mf].x, bvc[nf].x, acc[mf][nf], 0, 0, 0);
          acc[mf][nf] = __builtin_amdgcn_mfma_f32_16x16x32_fp8_fp8(av[mf].y, bvc[nf].y, acc[mf][nf], 0, 0, 0);
        }
      __builtin_amdgcn_s_setprio(0);
    }
    // second half: rows 64..127
    {
      long2 av[4];
#pragma unroll
      for (int mf = 0; mf < 4; ++mf) {
        int row = wm * 128 + (mf + 4) * 16 + lrow;
        av[mf] = *(const long2*)(Ab + row * 64 + ((lg ^ ((row >> 1) & 3)) << 4));
      }
      __builtin_amdgcn_s_setprio(1);
#pragma unroll
      for (int mf = 0; mf < 4; ++mf)
#pragma unroll
        for (int nf = 0; nf < 2; ++nf) {
          acc[mf + 4][nf] = __builtin_amdgcn_mfma_f32_16x16x32_fp8_fp8(av[mf].x, bvc[nf].x, acc[mf + 4][nf], 0, 0, 0);
          acc[mf + 4][nf] = __builtin_amdgcn_mfma_f32_16x16x32_fp8_fp8(av[mf].y, bvc[nf].y, acc[mf + 4][nf], 0, 0, 0);
        }
      __builtin_amdgcn_s_setprio(0);
    }
    bvc[0] = bvn[0]; bvc[1] = bvn[1];   // forces bvn wait here (post-MFMA)
  }

#pragma unroll
  for (int mf = 0; mf < 8; ++mf)
#pragma unroll
    for (int r = 0; r < 4; ++r) {
      int row = mtile * 256 + wm * 128 + mf * 16 + lg * 4 + r;
      const float* xr = X   + ((size_t)gb * 2048 + row) * 1024;
      float*      orp = Out + ((size_t)gb * 2048 + row) * 1024;
#pragma unroll
      for (int nf = 0; nf < 2; ++nf) {
        int col = ntile * 128 + wn * 32 + nf * 16 + lrow;
        orp[col] = acc[mf][nf][r] * 0.015625f + xr[col];   // /64 un-scale
      }
    }
}

extern "C" void kernel_launch(void* const* d_in, const int* in_sizes, int n_in,
                              void* d_out, int out_size, void* d_ws, size_t ws_size,
                              hipStream_t stream) {
  (void)in_sizes; (void)n_in; (void)out_size;
  const float* x  = (const float*)d_in[0];
  const float* y  = (const float*)d_in[1];
  const float* Wq = (const float*)d_in[2];
  const float* Wk = (const float*)d_in[3];
  const float* Wv = (const float*)d_in[4];
  float* out = (float*)d_out;

  // bf16 copies of x,y live in d_out during projections (overwritten later)
  unsigned short* xb = (unsigned short*)d_out;
  unsigned short* yb = xb + (size_t)16 * 2048 * 1024;

  // ws: Wqt | Wkt | Wvt (bf16) | q | k (bf16) | Vp (fp8 packed) | S (bf16) | P (fp8)
  char* p = (char*)d_ws;
  unsigned short* Wqt = (unsigned short*)p;  p += (size_t)256 * 1024 * 2;
  unsigned short* Wkt = (unsigned short*)p;  p += (size_t)256 * 1024 * 2;
  unsigned short* Wvt = (unsigned short*)p;  p += (size_t)1024 * 1024 * 2;
  unsigned short* qws = (unsigned short*)p;  p += (size_t)16 * 2048 * 256 * 2;
  unsigned short* kws = (unsigned short*)p;  p += (size_t)16 * 2048 * 256 * 2;
  unsigned char*  vp8 = (unsigned char*)p;   p += (size_t)16 * 1024 * 2048;
  char* dyn = p;
  const size_t fixed_bytes = (size_t)(dyn - (char*)d_ws);
  const size_t per_batch = (size_t)2048 * 2048 * 2 + (size_t)2048 * 2048;  // S + P
  int nb = 1;
  if      (ws_size >= fixed_bytes + 16 * per_batch) nb = 16;
  else if (ws_size >= fixed_bytes + 8  * per_batch) nb = 8;
  else if (ws_size >= fixed_bytes + 4  * per_batch) nb = 4;
  else if (ws_size >= fixed_bytes + 2  * per_batch) nb = 2;
  else nb = 1;
  unsigned short* Sp = (unsigned short*)dyn;
  unsigned char*  Pp = (unsigned char*)(dyn + (size_t)nb * 2048 * 2048 * 2);

  const int n8 = (16 * 2048 * 1024) / 8;
  cvt_bf16<<<2048, 256, 0, stream>>>(x, xb, n8);
  cvt_bf16<<<2048, 256, 0, stream>>>(y, yb, n8);
  tcvt<<<dim3(8, 32),  256, 0, stream>>>(Wq, Wqt, 1024, 256);
  tcvt<<<dim3(8, 32),  256, 0, stream>>>(Wk, Wkt, 1024, 256);
  tcvt<<<dim3(32, 32), 256, 0, stream>>>(Wv, Wvt, 1024, 1024);

  // q and k projections in ONE 256^2/4-phase launch: bid&1 selects q/k
  // (A stride = xb->yb, B stride = Wqt->Wkt, C stride = qws->kws)
  gemm4p<16, 1, 3><<<256, 512, 0, stream>>>(
      xb, Wqt, (size_t)16 * 2048 * 1024, (size_t)256 * 1024, 1024, 1024,
      qws, 0, 2);
  // V projection: 256^2 4-phase, fp8 packed epilogue (M=32768, N=1024, K=1024)
  gemm4p<16, 4, 2><<<512, 512, 0, stream>>>(
      yb, Wvt, 0, 0, 1024, 1024, (unsigned short*)vp8, 0, 1);

  for (int b0 = 0; b0 < 16; b0 += nb) {
    gemm4p<4, 8, 0><<<nb * 64, 512, 0, stream>>>(
        qws, kws, (size_t)2048 * 256, (size_t)2048 * 256, 256, 256,
        Sp, b0, nb);
    softmax_kernel<<<nb * 512, 256, 0, stream>>>(Sp, Pp);
    pvf8_kernel<<<nb * 64, 512, 0, stream>>>(Pp, vp8, x, out, b0, nb);
  }
}